// Round 9
// baseline (268.541 us; speedup 1.0000x reference)
//
#include <hip/hip_runtime.h>
#include <stdint.h>

#define T_TOTAL 4096
#define NT0     3072
#define CH      6144
#define TD_MAXL 1024

// ---- 256x256 band-Gram parameters ----
#define KS2    8            // K-split (ks bound to XCD)
#define KC2    (CH / KS2)   // 768 halfs per block
#define BK     32           // K per LDS step
#define NSTEP2 (KC2 / BK)   // 24
#define NI2    12           // I tiles (i < 3072, 256 rows each)
#define ND2    5            // D tiles (j-panel offset 256*D)
#define NBLK2  (NI2 * ND2 * KS2)   // 480

// ---- 128 fallback params ----
#define KSF    4
#define KCF    (CH / KSF)
#define NSTEPF (KCF / BK)
#define NDF    9
#define LDHF   40

typedef _Float16 half8 __attribute__((ext_vector_type(8)));
typedef float    f32x4 __attribute__((ext_vector_type(4)));

// d_ws: S f32[4096] @0 ; C f32[1024] @16384 ; xh fp16[4096*6144] @32768

__device__ inline void gload16(const void* g, void* l) {
    __builtin_amdgcn_global_load_lds(
        (const __attribute__((address_space(1))) unsigned int*)g,
        (__attribute__((address_space(3))) unsigned int*)l, 16, 0, 0);
}

__device__ inline half8 pack8(const float4 u, const float4 v) {
    half8 h;
    h[0] = (_Float16)u.x; h[1] = (_Float16)u.y; h[2] = (_Float16)u.z; h[3] = (_Float16)u.w;
    h[4] = (_Float16)v.x; h[5] = (_Float16)v.y; h[6] = (_Float16)v.z; h[7] = (_Float16)v.w;
    return h;   // RNE scalar cvt
}

// Fused: xh[t,:] = fp16(x[t,:]) ; S[t] = sum x^2 ; C init. One pass over x.
__global__ __launch_bounds__(256) void prep_kernel(const float* __restrict__ x,
                                                   _Float16* __restrict__ xh,
                                                   float* __restrict__ S,
                                                   float* __restrict__ C) {
    const int t = blockIdx.x;
    if (t < TD_MAXL && threadIdx.x == 0) C[t] = 0.0f;
    const float4* row = (const float4*)(x + (size_t)t * CH);
    _Float16* orow = xh + (size_t)t * CH;
    float s = 0.f;
    for (int k = threadIdx.x; k < CH / 8; k += 256) {   // 3 iters
        float4 u = row[2 * k], v = row[2 * k + 1];
        s = fmaf(u.x, u.x, s); s = fmaf(u.y, u.y, s);
        s = fmaf(u.z, u.z, s); s = fmaf(u.w, u.w, s);
        s = fmaf(v.x, v.x, s); s = fmaf(v.y, v.y, s);
        s = fmaf(v.z, v.z, s); s = fmaf(v.w, v.w, s);
        *(half8*)(orow + 8 * k) = pack8(u, v);
    }
    #pragma unroll
    for (int off = 32; off >= 1; off >>= 1) s += __shfl_xor(s, off, 64);
    __shared__ float part[4];
    const int lane = threadIdx.x & 63, wid = threadIdx.x >> 6;
    if (lane == 0) part[wid] = s;
    __syncthreads();
    if (threadIdx.x == 0) S[t] = part[0] + part[1] + part[2] + part[3];
}

// 256x256 band-Gram tile, 8 waves. Tile (I,D): i in [256I,+256),
// j in [256(I+D),+256); each (i,j) pair with td=j-i in [0,1024) lives in
// EXACTLY one tile (D = (j>>8)-(i>>8) <= 4). Wave (wm,wn) = 128x64 quadrant.
// ks = XCD id -> per-XCD K-slice: footprint 6 MB, heavy L2 reuse.
// Staging: global_load_lds w16, linear LDS [256][32], both-sides XOR swizzle
// (R8-verified). Traffic: 480 blk x 24 chunks x 32 KB = 368 MB (was 664).
__global__ __launch_bounds__(512, 2) void cross_mfma2(const _Float16* __restrict__ xh,
                                                      float* __restrict__ C) {
    __shared__ _Float16 Ps[2][2][256][BK];   // [buf][panel A/B][row][col] = 64 KB
    __shared__ float    C_loc[512];

    const int tid = threadIdx.x;
    const int bid = blockIdx.x;            // 0..479
    const int ks   = bid & 7;              // = XCD (HW %8 round-robin)
    const int slot = bid >> 3;             // 0..59
    const int I    = slot / ND2;           // 0..11
    const int D    = slot % ND2;           // 0..4
    const int i0 = I * 256, j0 = (I + D) * 256;
    const int k0 = ks * KC2;

    if (tid < 512) C_loc[tid] = 0.f;

    const int lane = tid & 63, wid = tid >> 6;

    // ---- staging (waves 0-3: A panel, 4-7: B panel; 64 rows each) ----
    const int isB  = wid >> 2;             // 0=A, 1=B
    const int wq   = wid & 3;              // 64-row group within panel
    const int rsub = lane >> 2;            // row within 16-row chunk
    const int pslot= lane & 3;             // physical 16B slot lane fills
    const int swz  = (pslot ^ (rsub & 3)) << 3;   // swizzled col (halfs)
    const _Float16* src0 = xh
        + (size_t)((isB ? j0 : i0) + wq * 64 + rsub) * CH + k0 + swz;

#define STAGE(buf, t) { \
        gload16(src0 + (size_t)(t) * BK,               &Ps[buf][isB][wq * 64][0]);      \
        gload16(src0 + (size_t)(t) * BK + 16 * CH,     &Ps[buf][isB][wq * 64 + 16][0]); \
        gload16(src0 + (size_t)(t) * BK + 32 * CH,     &Ps[buf][isB][wq * 64 + 32][0]); \
        gload16(src0 + (size_t)(t) * BK + 48 * CH,     &Ps[buf][isB][wq * 64 + 48][0]); \
    }

    // ---- fragment addressing ----
    const int wm = wid >> 2, wn = wid & 3;           // 2x4 waves, 128x64 quadrant
    const int fr = lane & 15, ss = lane >> 4;
    const int rdslot = (ss ^ (fr & 3)) << 4;         // byte offset of 16B slot
    const int offA = (wm * 128 + fr) * (BK * 2) + rdslot;   // + m*16 rows
    const int offB = (wn * 64 + fr) * (BK * 2) + rdslot;    // + n*16 rows

    f32x4 acc[8][4];
    #pragma unroll
    for (int m = 0; m < 8; ++m)
        #pragma unroll
        for (int n = 0; n < 4; ++n) acc[m][n] = (f32x4)0.f;

    STAGE(0, 0);
    __syncthreads();

    int cur = 0;
    for (int t = 0; t < NSTEP2; ++t) {
        if (t + 1 < NSTEP2) STAGE(cur ^ 1, t + 1);   // DMA hidden under MFMA

        const char* bA = (const char*)&Ps[cur][0][0][0];
        const char* bB = (const char*)&Ps[cur][1][0][0];
        half8 fA[8], fB[4];
        #pragma unroll
        for (int m = 0; m < 8; ++m)
            fA[m] = *(const half8*)(bA + offA + m * (16 * BK * 2));
        #pragma unroll
        for (int n = 0; n < 4; ++n)
            fB[n] = *(const half8*)(bB + offB + n * (16 * BK * 2));
        #pragma unroll
        for (int m = 0; m < 8; ++m)
            #pragma unroll
            for (int n = 0; n < 4; ++n)
                acc[m][n] = __builtin_amdgcn_mfma_f32_16x16x32_f16(fA[m], fB[n],
                                                                   acc[m][n], 0, 0, 0);
        __syncthreads();
        cur ^= 1;
    }
#undef STAGE

    // epilogue: i_loc = 128wm+16m+4ss+rr, j_loc = 64wn+16n+fr
    // o = j_loc-i_loc in (-256,256); slot = o+255 in [0,511)
    float buck[11][4];
    #pragma unroll
    for (int dd = 0; dd < 11; ++dd)
        #pragma unroll
        for (int rr = 0; rr < 4; ++rr) buck[dd][rr] = 0.f;
    #pragma unroll
    for (int m = 0; m < 8; ++m)
        #pragma unroll
        for (int n = 0; n < 4; ++n)
            #pragma unroll
            for (int rr = 0; rr < 4; ++rr)
                buck[n - m + 7][rr] += acc[m][n][rr];

    const int obase = 64 * wn - 128 * wm + 255 + (fr - (ss << 2));
    #pragma unroll
    for (int dd = 0; dd < 11; ++dd)
        #pragma unroll
        for (int rr = 0; rr < 4; ++rr)
            atomicAdd(&C_loc[obase + 16 * (dd - 7) - rr], buck[dd][rr]);
    __syncthreads();

    if (tid < 511) {
        const int td = D * 256 + tid - 255;   // masks D=0 lower tri & td>=1024
        if (td >= 0 && td < TD_MAXL) atomicAdd(&C[td], C_loc[tid]);
    }
}

// ---- fallback (R7-verified, fp32 input, no ws needed) ----
__global__ __launch_bounds__(256, 2) void cross_fallback(const float* __restrict__ x,
                                                         float* __restrict__ C) {
    __shared__ _Float16 As[2][128][LDHF];
    __shared__ _Float16 Bs[2][128][LDHF];
    __shared__ float    C_loc[256];
    const int tid = threadIdx.x;
    const int bid = blockIdx.x;
    const int xcd  = bid & 7;
    const int slot = bid >> 3;
    const int ks   = slot / 27;
    const int tt   = slot % 27;
    const int tile = xcd * 27 + tt;
    const int I    = tile / NDF;
    const int D    = tile % NDF;
    const int i0 = I * 128, j0 = (I + D) * 128;
    const int k0 = ks * KCF;
    C_loc[tid] = 0.f;
    const int srow = tid >> 1, skq = (tid & 1) << 4;
    const float* gA = x + (size_t)(i0 + srow) * CH + k0 + skq;
    const float* gB = x + (size_t)(j0 + srow) * CH + k0 + skq;
    const int lane = tid & 63, wid = tid >> 6;
    const int wm = wid >> 1, wn = wid & 1;
    const int fr = lane & 15, ss = lane >> 4;
    const int rowA = wm * 64 + fr, rowB = wn * 64 + fr;
    f32x4 acc[4][4];
    #pragma unroll
    for (int m = 0; m < 4; ++m)
        #pragma unroll
        for (int n = 0; n < 4; ++n) acc[m][n] = (f32x4)0.f;
    {
        float4 a[4], b[4];
        #pragma unroll
        for (int q = 0; q < 4; ++q) { a[q] = ((const float4*)gA)[q]; b[q] = ((const float4*)gB)[q]; }
        *(half8*)&As[0][srow][skq]     = pack8(a[0], a[1]);
        *(half8*)&As[0][srow][skq + 8] = pack8(a[2], a[3]);
        *(half8*)&Bs[0][srow][skq]     = pack8(b[0], b[1]);
        *(half8*)&Bs[0][srow][skq + 8] = pack8(b[2], b[3]);
    }
    int cur = 0;
    for (int t = 0; t < NSTEPF; ++t) {
        __syncthreads();
        float4 a[4], b[4];
        const bool more = (t + 1 < NSTEPF);
        if (more) {
            const float* pA = gA + (size_t)(t + 1) * BK;
            const float* pB = gB + (size_t)(t + 1) * BK;
            #pragma unroll
            for (int q = 0; q < 4; ++q) { a[q] = ((const float4*)pA)[q]; b[q] = ((const float4*)pB)[q]; }
        }
        half8 fA[4], fB[4];
        #pragma unroll
        for (int m = 0; m < 4; ++m) fA[m] = *(const half8*)&As[cur][rowA + 16 * m][ss * 8];
        #pragma unroll
        for (int n = 0; n < 4; ++n) fB[n] = *(const half8*)&Bs[cur][rowB + 16 * n][ss * 8];
        #pragma unroll
        for (int m = 0; m < 4; ++m)
            #pragma unroll
            for (int n = 0; n < 4; ++n)
                acc[m][n] = __builtin_amdgcn_mfma_f32_16x16x32_f16(fA[m], fB[n], acc[m][n], 0, 0, 0);
        if (more) {
            const int nb = cur ^ 1;
            *(half8*)&As[nb][srow][skq]     = pack8(a[0], a[1]);
            *(half8*)&As[nb][srow][skq + 8] = pack8(a[2], a[3]);
            *(half8*)&Bs[nb][srow][skq]     = pack8(b[0], b[1]);
            *(half8*)&Bs[nb][srow][skq + 8] = pack8(b[2], b[3]);
        }
        cur ^= 1;
    }
    float buck[7][4];
    #pragma unroll
    for (int dd = 0; dd < 7; ++dd)
        #pragma unroll
        for (int rr = 0; rr < 4; ++rr) buck[dd][rr] = 0.f;
    #pragma unroll
    for (int m = 0; m < 4; ++m)
        #pragma unroll
        for (int n = 0; n < 4; ++n)
            #pragma unroll
            for (int rr = 0; rr < 4; ++rr)
                buck[n - m + 3][rr] += acc[m][n][rr];
    const int obase = 64 * (wn - wm) + 128 + (fr - (ss << 2));
    #pragma unroll
    for (int dd = 0; dd < 7; ++dd)
        #pragma unroll
        for (int rr = 0; rr < 4; ++rr)
            atomicAdd(&C_loc[obase + 16 * (dd - 3) - rr], buck[dd][rr]);
    __syncthreads();
    const int td = D * 128 + tid - 128;
    if (td >= 0 && td < TD_MAXL) atomicAdd(&C[td], C_loc[tid]);
}

// msd[td] = (P[td] + Q - 2*C[td]) / (NT0*CH) — one block per td
__global__ __launch_bounds__(256) void combine_kernel(const float* __restrict__ S,
                                                      const float* __restrict__ C,
                                                      float* __restrict__ out) {
    const int td = blockIdx.x;
    float p = 0.f, q = 0.f;
    for (int t = threadIdx.x; t < NT0; t += 256) {
        p += S[t + td];
        q += S[t];
    }
    #pragma unroll
    for (int off = 32; off >= 1; off >>= 1) {
        p += __shfl_xor(p, off, 64);
        q += __shfl_xor(q, off, 64);
    }
    __shared__ float pp[4], qq[4];
    const int lane = threadIdx.x & 63, wid = threadIdx.x >> 6;
    if (lane == 0) { pp[wid] = p; qq[wid] = q; }
    __syncthreads();
    if (threadIdx.x == 0) {
        const float P = pp[0] + pp[1] + pp[2] + pp[3];
        const float Q = qq[0] + qq[1] + qq[2] + qq[3];
        const float inv_M = 1.0f / ((float)NT0 * (float)CH);
        out[td] = (P + Q - 2.0f * C[td]) * inv_M;
    }
}

extern "C" void kernel_launch(void* const* d_in, const int* in_sizes, int n_in,
                              void* d_out, int out_size, void* d_ws, size_t ws_size,
                              hipStream_t stream) {
    const float* x = (const float*)d_in[0];
    float* out = (float*)d_out;
    float* S = (float*)d_ws;                               // 4096 f32
    float* C = (float*)((char*)d_ws + 16384);              // 1024 f32
    _Float16* xh = (_Float16*)((char*)d_ws + 32768);       // 50.3 MB fp16 copy
    const size_t need = 32768 + (size_t)T_TOTAL * CH * sizeof(_Float16);

    if (ws_size >= need) {
        prep_kernel<<<dim3(T_TOTAL), dim3(256), 0, stream>>>(x, xh, S, C);
        cross_mfma2<<<dim3(NBLK2), dim3(512), 0, stream>>>(xh, C);
    } else {
        prep_kernel<<<dim3(T_TOTAL), dim3(256), 0, stream>>>(x, xh, S, C); // xh unused below
        cross_fallback<<<dim3(216 * KSF), dim3(256), 0, stream>>>(x, C);
    }
    combine_kernel<<<dim3(TD_MAXL), dim3(256), 0, stream>>>(S, C, out);
}

// Round 10
// 240.062 us; speedup vs baseline: 1.1186x; 1.1186x over previous
//
#include <hip/hip_runtime.h>
#include <stdint.h>

#define T_TOTAL 4096
#define NT0     3072
#define CH      6144
#define TD_MAXL 1024

// ---- 256x256 band-Gram parameters ----
#define KS2    4            // K-split (ks = xcd>>1: XCD-pair bound K-chunk)
#define KC2    (CH / KS2)   // 1536 halfs per block
#define BK     32           // K per LDS step
#define NSTEP2 (KC2 / BK)   // 48
#define NI2    12           // I tiles (i < 3072, 256 rows each)
#define ND2    5            // D tiles
#define NBLK2  240          // 12*5*4 — single generation at 1 block/CU

// ---- 128 fallback params ----
#define KSF    4
#define KCF    (CH / KSF)
#define NSTEPF (KCF / BK)
#define NDF    9
#define LDHF   40

typedef _Float16 half8 __attribute__((ext_vector_type(8)));
typedef float    f32x4 __attribute__((ext_vector_type(4)));

// d_ws: S f32[4096] @0 ; C f32[1024] @16384 ; xh fp16[4096*6144] @32768

__device__ inline void gload16(const void* g, void* l) {
    __builtin_amdgcn_global_load_lds(
        (const __attribute__((address_space(1))) unsigned int*)g,
        (__attribute__((address_space(3))) unsigned int*)l, 16, 0, 0);
}

__device__ inline half8 pack8(const float4 u, const float4 v) {
    half8 h;
    h[0] = (_Float16)u.x; h[1] = (_Float16)u.y; h[2] = (_Float16)u.z; h[3] = (_Float16)u.w;
    h[4] = (_Float16)v.x; h[5] = (_Float16)v.y; h[6] = (_Float16)v.z; h[7] = (_Float16)v.w;
    return h;   // RNE scalar cvt
}

// Fused: xh[t,:] = fp16(x[t,:]) ; S[t] = sum x^2 ; C init. (R9-identical)
__global__ __launch_bounds__(256) void prep_kernel(const float* __restrict__ x,
                                                   _Float16* __restrict__ xh,
                                                   float* __restrict__ S,
                                                   float* __restrict__ C) {
    const int t = blockIdx.x;
    if (t < TD_MAXL && threadIdx.x == 0) C[t] = 0.0f;
    const float4* row = (const float4*)(x + (size_t)t * CH);
    _Float16* orow = xh + (size_t)t * CH;
    float s = 0.f;
    for (int k = threadIdx.x; k < CH / 8; k += 256) {
        float4 u = row[2 * k], v = row[2 * k + 1];
        s = fmaf(u.x, u.x, s); s = fmaf(u.y, u.y, s);
        s = fmaf(u.z, u.z, s); s = fmaf(u.w, u.w, s);
        s = fmaf(v.x, v.x, s); s = fmaf(v.y, v.y, s);
        s = fmaf(v.z, v.z, s); s = fmaf(v.w, v.w, s);
        *(half8*)(orow + 8 * k) = pack8(u, v);
    }
    #pragma unroll
    for (int off = 32; off >= 1; off >>= 1) s += __shfl_xor(s, off, 64);
    __shared__ float part[4];
    const int lane = threadIdx.x & 63, wid = threadIdx.x >> 6;
    if (lane == 0) part[wid] = s;
    __syncthreads();
    if (threadIdx.x == 0) S[t] = part[0] + part[1] + part[2] + part[3];
}

// 256x256 band-Gram tile, 8 waves (R9 geometry) with a COUNTED-vmcnt
// double-barrier pipeline (T4): next-step global_load_lds DMA stays in
// flight across the barrier; each wave waits only for the PREVIOUS step's
// 4 loads (vmcnt(4)). __syncthreads (vmcnt(0) drain) eliminated from the
// main loop — that drain was R9's 11.8K-cyc/step stall.
// Swizzle: 16B-slot involution p = c ^ ((row>>1)&3) on both write (global
// source pre-swizzle) and read sides -> u = 4*fr + slot is a lane bijection
// -> zero LDS bank conflicts (R9's (row&3) XOR was 4-way-colliding).
__global__ __launch_bounds__(512, 2) void cross_mfma2(const _Float16* __restrict__ xh,
                                                      float* __restrict__ C) {
    __shared__ _Float16 Ps[2][2][256][BK];   // [buf][A/B][row][col] = 64 KB
    __shared__ float    C_loc[512];

    const int tid = threadIdx.x;
    const int bid = blockIdx.x;            // 0..239
    const int xcd  = bid & 7;              // HW %8 XCD round-robin
    const int slot = bid >> 3;             // 0..29
    const int ks   = xcd >> 1;             // 0..3: XCD pair owns one K-chunk
    const int tile = (xcd & 1) * 30 + slot;// 0..59 (bijective)
    const int I    = tile / ND2;           // 0..11
    const int D    = tile % ND2;           // 0..4
    const int i0 = I * 256, j0 = (I + D) * 256;
    const int k0 = ks * KC2;

    C_loc[tid] = 0.f;

    const int lane = tid & 63, wid = tid >> 6;

    // ---- staging (waves 0-3: A panel, 4-7: B panel; 64 rows each) ----
    const int isB  = wid >> 2;
    const int wq   = wid & 3;
    const int rsub = lane >> 2;            // row within 16-row chunk
    const int pslot= lane & 3;             // physical 16B slot lane fills
    const int swz  = (pslot ^ ((rsub >> 1) & 3)) << 3;   // inverse-swz src col
    const _Float16* src0 = xh
        + (size_t)((isB ? j0 : i0) + wq * 64 + rsub) * CH + k0 + swz;

#define STAGE(buf, t) { \
        gload16(src0 + (size_t)(t) * BK,               &Ps[buf][isB][wq * 64][0]);      \
        gload16(src0 + (size_t)(t) * BK + 16 * CH,     &Ps[buf][isB][wq * 64 + 16][0]); \
        gload16(src0 + (size_t)(t) * BK + 32 * CH,     &Ps[buf][isB][wq * 64 + 32][0]); \
        gload16(src0 + (size_t)(t) * BK + 48 * CH,     &Ps[buf][isB][wq * 64 + 48][0]); \
    }

    // ---- fragment addressing (swizzled read, zero-conflict) ----
    const int wm = wid >> 2, wn = wid & 3;           // 2x4 waves, 128x64 quadrant
    const int fr = lane & 15, ss = lane >> 4;
    const int rdslot = (ss ^ ((fr >> 1) & 3)) << 4;  // byte offset of 16B slot
    const int offA = (wm * 128 + fr) * (BK * 2) + rdslot;   // + m*16 rows
    const int offB = (wn * 64 + fr) * (BK * 2) + rdslot;    // + n*16 rows

    f32x4 acc[8][4];
    #pragma unroll
    for (int m = 0; m < 8; ++m)
        #pragma unroll
        for (int n = 0; n < 4; ++n) acc[m][n] = (f32x4)0.f;

    STAGE(0, 0);

    int cur = 0;
    for (int t = 0; t < NSTEP2; ++t) {
        if (t + 1 < NSTEP2) {
            STAGE(cur ^ 1, t + 1);                      // 4 new loads in flight
            asm volatile("s_waitcnt vmcnt(4)" ::: "memory");  // prev 4 landed
        } else {
            asm volatile("s_waitcnt vmcnt(0)" ::: "memory");
        }
        __builtin_amdgcn_s_barrier();                   // all waves: buf[cur] ready
        __builtin_amdgcn_sched_barrier(0);              // no ds_read hoisted above

        const char* bA = (const char*)&Ps[cur][0][0][0];
        const char* bB = (const char*)&Ps[cur][1][0][0];
        half8 fA[8], fB[4];
        #pragma unroll
        for (int m = 0; m < 8; ++m)
            fA[m] = *(const half8*)(bA + offA + m * (16 * BK * 2));
        #pragma unroll
        for (int n = 0; n < 4; ++n)
            fB[n] = *(const half8*)(bB + offB + n * (16 * BK * 2));
        #pragma unroll
        for (int m = 0; m < 8; ++m)
            #pragma unroll
            for (int n = 0; n < 4; ++n)
                acc[m][n] = __builtin_amdgcn_mfma_f32_16x16x32_f16(fA[m], fB[n],
                                                                   acc[m][n], 0, 0, 0);

        __builtin_amdgcn_sched_barrier(0);              // no ds_read sunk below
        __builtin_amdgcn_s_barrier();                   // all done reading buf[cur]
        cur ^= 1;
    }
#undef STAGE

    // epilogue (R9-verified): i_loc = 128wm+16m+4ss+rr, j_loc = 64wn+16n+fr
    float buck[11][4];
    #pragma unroll
    for (int dd = 0; dd < 11; ++dd)
        #pragma unroll
        for (int rr = 0; rr < 4; ++rr) buck[dd][rr] = 0.f;
    #pragma unroll
    for (int m = 0; m < 8; ++m)
        #pragma unroll
        for (int n = 0; n < 4; ++n)
            #pragma unroll
            for (int rr = 0; rr < 4; ++rr)
                buck[n - m + 7][rr] += acc[m][n][rr];

    const int obase = 64 * wn - 128 * wm + 255 + (fr - (ss << 2));
    #pragma unroll
    for (int dd = 0; dd < 11; ++dd)
        #pragma unroll
        for (int rr = 0; rr < 4; ++rr)
            atomicAdd(&C_loc[obase + 16 * (dd - 7) - rr], buck[dd][rr]);
    __syncthreads();

    if (tid < 511) {
        const int td = D * 256 + tid - 255;   // masks D=0 lower tri & td>=1024
        if (td >= 0 && td < TD_MAXL) atomicAdd(&C[td], C_loc[tid]);
    }
}

// ---- fallback (R7-verified, fp32 input, no big ws needed) ----
__global__ __launch_bounds__(256, 2) void cross_fallback(const float* __restrict__ x,
                                                         float* __restrict__ C) {
    __shared__ _Float16 As[2][128][LDHF];
    __shared__ _Float16 Bs[2][128][LDHF];
    __shared__ float    C_loc[256];
    const int tid = threadIdx.x;
    const int bid = blockIdx.x;
    const int xcd  = bid & 7;
    const int slot = bid >> 3;
    const int ks   = slot / 27;
    const int tt   = slot % 27;
    const int tile = xcd * 27 + tt;
    const int I    = tile / NDF;
    const int D    = tile % NDF;
    const int i0 = I * 128, j0 = (I + D) * 128;
    const int k0 = ks * KCF;
    C_loc[tid] = 0.f;
    const int srow = tid >> 1, skq = (tid & 1) << 4;
    const float* gA = x + (size_t)(i0 + srow) * CH + k0 + skq;
    const float* gB = x + (size_t)(j0 + srow) * CH + k0 + skq;
    const int lane = tid & 63, wid = tid >> 6;
    const int wm = wid >> 1, wn = wid & 1;
    const int fr = lane & 15, ss = lane >> 4;
    const int rowA = wm * 64 + fr, rowB = wn * 64 + fr;
    f32x4 acc[4][4];
    #pragma unroll
    for (int m = 0; m < 4; ++m)
        #pragma unroll
        for (int n = 0; n < 4; ++n) acc[m][n] = (f32x4)0.f;
    {
        float4 a[4], b[4];
        #pragma unroll
        for (int q = 0; q < 4; ++q) { a[q] = ((const float4*)gA)[q]; b[q] = ((const float4*)gB)[q]; }
        *(half8*)&As[0][srow][skq]     = pack8(a[0], a[1]);
        *(half8*)&As[0][srow][skq + 8] = pack8(a[2], a[3]);
        *(half8*)&Bs[0][srow][skq]     = pack8(b[0], b[1]);
        *(half8*)&Bs[0][srow][skq + 8] = pack8(b[2], b[3]);
    }
    int cur = 0;
    for (int t = 0; t < NSTEPF; ++t) {
        __syncthreads();
        float4 a[4], b[4];
        const bool more = (t + 1 < NSTEPF);
        if (more) {
            const float* pA = gA + (size_t)(t + 1) * BK;
            const float* pB = gB + (size_t)(t + 1) * BK;
            #pragma unroll
            for (int q = 0; q < 4; ++q) { a[q] = ((const float4*)pA)[q]; b[q] = ((const float4*)pB)[q]; }
        }
        half8 fA[4], fB[4];
        #pragma unroll
        for (int m = 0; m < 4; ++m) fA[m] = *(const half8*)&As[cur][rowA + 16 * m][ss * 8];
        #pragma unroll
        for (int n = 0; n < 4; ++n) fB[n] = *(const half8*)&Bs[cur][rowB + 16 * n][ss * 8];
        #pragma unroll
        for (int m = 0; m < 4; ++m)
            #pragma unroll
            for (int n = 0; n < 4; ++n)
                acc[m][n] = __builtin_amdgcn_mfma_f32_16x16x32_f16(fA[m], fB[n], acc[m][n], 0, 0, 0);
        if (more) {
            const int nb = cur ^ 1;
            *(half8*)&As[nb][srow][skq]     = pack8(a[0], a[1]);
            *(half8*)&As[nb][srow][skq + 8] = pack8(a[2], a[3]);
            *(half8*)&Bs[nb][srow][skq]     = pack8(b[0], b[1]);
            *(half8*)&Bs[nb][srow][skq + 8] = pack8(b[2], b[3]);
        }
        cur ^= 1;
    }
    float buck[7][4];
    #pragma unroll
    for (int dd = 0; dd < 7; ++dd)
        #pragma unroll
        for (int rr = 0; rr < 4; ++rr) buck[dd][rr] = 0.f;
    #pragma unroll
    for (int m = 0; m < 4; ++m)
        #pragma unroll
        for (int n = 0; n < 4; ++n)
            #pragma unroll
            for (int rr = 0; rr < 4; ++rr)
                buck[n - m + 3][rr] += acc[m][n][rr];
    const int obase = 64 * (wn - wm) + 128 + (fr - (ss << 2));
    #pragma unroll
    for (int dd = 0; dd < 7; ++dd)
        #pragma unroll
        for (int rr = 0; rr < 4; ++rr)
            atomicAdd(&C_loc[obase + 16 * (dd - 3) - rr], buck[dd][rr]);
    __syncthreads();
    const int td = D * 128 + tid - 128;
    if (td >= 0 && td < TD_MAXL) atomicAdd(&C[td], C_loc[tid]);
}

// msd[td] = (P[td] + Q - 2*C[td]) / (NT0*CH) — one block per td (R9-identical)
__global__ __launch_bounds__(256) void combine_kernel(const float* __restrict__ S,
                                                      const float* __restrict__ C,
                                                      float* __restrict__ out) {
    const int td = blockIdx.x;
    float p = 0.f, q = 0.f;
    for (int t = threadIdx.x; t < NT0; t += 256) {
        p += S[t + td];
        q += S[t];
    }
    #pragma unroll
    for (int off = 32; off >= 1; off >>= 1) {
        p += __shfl_xor(p, off, 64);
        q += __shfl_xor(q, off, 64);
    }
    __shared__ float pp[4], qq[4];
    const int lane = threadIdx.x & 63, wid = threadIdx.x >> 6;
    if (lane == 0) { pp[wid] = p; qq[wid] = q; }
    __syncthreads();
    if (threadIdx.x == 0) {
        const float P = pp[0] + pp[1] + pp[2] + pp[3];
        const float Q = qq[0] + qq[1] + qq[2] + qq[3];
        const float inv_M = 1.0f / ((float)NT0 * (float)CH);
        out[td] = (P + Q - 2.0f * C[td]) * inv_M;
    }
}

extern "C" void kernel_launch(void* const* d_in, const int* in_sizes, int n_in,
                              void* d_out, int out_size, void* d_ws, size_t ws_size,
                              hipStream_t stream) {
    const float* x = (const float*)d_in[0];
    float* out = (float*)d_out;
    float* S = (float*)d_ws;                               // 4096 f32
    float* C = (float*)((char*)d_ws + 16384);              // 1024 f32
    _Float16* xh = (_Float16*)((char*)d_ws + 32768);       // 50.3 MB fp16 copy
    const size_t need = 32768 + (size_t)T_TOTAL * CH * sizeof(_Float16);

    if (ws_size >= need) {
        prep_kernel<<<dim3(T_TOTAL), dim3(256), 0, stream>>>(x, xh, S, C);
        cross_mfma2<<<dim3(NBLK2), dim3(512), 0, stream>>>(xh, C);
    } else {
        prep_kernel<<<dim3(T_TOTAL), dim3(256), 0, stream>>>(x, xh, S, C); // xh unused below
        cross_fallback<<<dim3(216 * KSF), dim3(256), 0, stream>>>(x, C);
    }
    combine_kernel<<<dim3(TD_MAXL), dim3(256), 0, stream>>>(S, C, out);
}